// Round 14
// baseline (460.016 us; speedup 1.0000x reference)
//
#include <hip/hip_runtime.h>
#include <hip/hip_fp16.h>
#include <hip/hip_cooperative_groups.h>
#include <cstddef>

namespace cg = cooperative_groups;

// ICTDIrrepsE3Conv — round 14: cooperative mega-kernel (6 launches -> 1).
//  Round 13 post-mortem: record-size change neutral -> gather not traffic-
//  bound; budget arithmetic says ~half of dur_us is launch overhead
//  (round 9: -2 launches = -18us). Fuse everything; grid.sync() between
//  phases. Fallback to the proven 6-kernel path if cooperative launch fails.

#define TBL_N 8192
#define TBL_SCALE 1024.0f

__device__ __forceinline__ float silu(float x) {
    return x / (1.0f + __expf(-x));
}

__device__ __forceinline__ unsigned pack_half2(float lo, float hi) {
    unsigned a = __half_as_ushort(__float2half_rn(lo));
    unsigned b = __half_as_ushort(__float2half_rn(hi));
    return (b << 16) | a;
}

// ---------- shared device helpers (used by mega + fallback) ----------

__device__ __forceinline__ void table_group(
    int samp, int s, int k,
    const float* fc_w1, const float* fc_b1,
    const float* fc_w2, const float* fc_b2,
    const float* fc_w3, const float* fc_b3,
    float4* table, float (*s_h1)[64])
{
    float len = (float)samp * (1.0f / TBL_SCALE);
    float emb[16];
    const float inv_step = 17.0f / 5.0f;
    #pragma unroll
    for (int b = 0; b < 16; b++) {
        float d = len * inv_step - (float)(b + 1);
        emb[b] = __expf(-d * d) * 3.5714285714285716f; // 4/1.12
    }
    float acc = fc_b1[k];
    #pragma unroll
    for (int b = 0; b < 16; b++) acc = fmaf(emb[b], fc_w1[b * 64 + k], acc);
    s_h1[s][k] = silu(acc);
    __syncthreads();
    float acc2 = fc_b2[k];
    #pragma unroll
    for (int j = 0; j < 64; j++)
        acc2 = fmaf(s_h1[s][j], fc_w2[j * 64 + k], acc2);
    float h2 = silu(acc2);
    float p0 = h2 * fc_w3[k * 15 + 0];
    float p3 = h2 * fc_w3[k * 15 + 3];
    float p9 = h2 * fc_w3[k * 15 + 9];
    #pragma unroll
    for (int off = 32; off > 0; off >>= 1) {
        p0 += __shfl_down(p0, off, 64);
        p3 += __shfl_down(p3, off, 64);
        p9 += __shfl_down(p9, off, 64);
    }
    if (k == 0) {
        table[samp] = make_float4((fc_b3[0] + p0) * 0.125f,
                                  (fc_b3[3] + p3) * 0.125f,
                                  (fc_b3[9] + p9) * 0.125f, 0.0f);
    }
}

__device__ __forceinline__ void edge_work(
    int e,
    const float* pos, const int* A, const int* batch,
    const int* edge_src, const int* edge_dst,
    const float* edge_shifts, const float* cell,
    const float4* table, const int* starts, const int* rank,
    unsigned* records)
{
    int src = edge_src[e];
    int dst = edge_dst[e];

    float sh0 = edge_shifts[3 * (size_t)e + 0];
    float sh1 = edge_shifts[3 * (size_t)e + 1];
    float sh2 = edge_shifts[3 * (size_t)e + 2];
    int g = batch[src];
    const float* C = cell + (size_t)g * 9;
    float shx = sh0 * C[0] + sh1 * C[3] + sh2 * C[6];
    float shy = sh0 * C[1] + sh1 * C[4] + sh2 * C[7];
    float shz = sh0 * C[2] + sh1 * C[5] + sh2 * C[8];

    float vx = pos[3 * (size_t)dst + 0] - pos[3 * (size_t)src + 0] + shx;
    float vy = pos[3 * (size_t)dst + 1] - pos[3 * (size_t)src + 1] + shy;
    float vz = pos[3 * (size_t)dst + 2] - pos[3 * (size_t)src + 2] + shz;

    float len = sqrtf(vx * vx + vy * vy + vz * vz);
    float invl = 1.0f / fmaxf(len, 1e-8f);
    float nx = vx * invl, ny = vy * invl, nz = vz * invl;

    float t = fminf(len * TBL_SCALE, (float)(TBL_N - 1));
    int i0 = (int)t;
    i0 = min(i0, TBL_N - 2);
    float fr = t - (float)i0;
    float4 T0 = table[i0];
    float4 T1 = table[i0 + 1];
    float g0 = fmaf(fr, T1.x - T0.x, T0.x);
    float g1 = fmaf(fr, T1.y - T0.y, T0.y);
    float g2 = fmaf(fr, T1.z - T0.z, T0.z);

    const float s3  = 1.7320508075688772f;
    const float s15 = 3.872983346207417f;
    const float s5  = 2.23606797749979f;
    float G0 = g0;
    float G1 = g1 * s3 * ny, G2 = g1 * s3 * nz, G3 = g1 * s3 * nx;
    float G4 = g2 * s15 * nx * ny;
    float G5 = g2 * s15 * ny * nz;
    float G6 = g2 * 0.5f * s5 * (3.0f * nz * nz - 1.0f);
    float G7 = g2 * s15 * nx * nz;
    float G8 = g2 * 0.5f * s15 * (nx * nx - ny * ny);

    int asrc = A[src];
    int slot = starts[dst] + rank[e];

    uint4* r = (uint4*)(records + (size_t)slot * 8);
    r[0] = make_uint4(pack_half2(G0, G8), pack_half2(G1, (float)asrc),
                      pack_half2(G2, 0.0f), pack_half2(G3, 0.0f));
    r[1] = make_uint4(pack_half2(G4, 0.0f), pack_half2(G5, 0.0f),
                      pack_half2(G6, 0.0f), pack_half2(G7, 0.0f));
}

__device__ __forceinline__ void gather_node(
    int node, int wv, int lane, int iq, int u,
    const unsigned* records, const int* starts, const int* deg, const int* A,
    const float* s_B, const float* s_rows, float (*s_M)[80], float* out)
{
    int start = starts[node];
    int d = deg[node];
    int anode = A[node];

    float m = 0.0f, m8 = 0.0f;
    const unsigned* recs = records + (size_t)start * 8;
    int j = 0;
    for (; j + 4 <= d; j += 4) {
        unsigned q0 = recs[((size_t)(j + 0) << 3) + iq];
        unsigned q1 = recs[((size_t)(j + 1) << 3) + iq];
        unsigned q2 = recs[((size_t)(j + 2) << 3) + iq];
        unsigned q3 = recs[((size_t)(j + 3) << 3) + iq];
        float2 p0 = __half22float2(*reinterpret_cast<const __half2*>(&q0));
        float2 p1 = __half22float2(*reinterpret_cast<const __half2*>(&q1));
        float2 p2 = __half22float2(*reinterpret_cast<const __half2*>(&q2));
        float2 p3 = __half22float2(*reinterpret_cast<const __half2*>(&q3));
        int a0 = (int)__shfl(p0.y, 8, 64);
        int a1 = (int)__shfl(p1.y, 8, 64);
        int a2 = (int)__shfl(p2.y, 8, 64);
        int a3 = (int)__shfl(p3.y, 8, 64);
        float c0 = s_rows[a0 * 8 + u];
        float c1 = s_rows[a1 * 8 + u];
        float c2 = s_rows[a2 * 8 + u];
        float c3 = s_rows[a3 * 8 + u];
        m  = fmaf(p0.x, c0, m);  m8 = fmaf(p0.y, c0, m8);
        m  = fmaf(p1.x, c1, m);  m8 = fmaf(p1.y, c1, m8);
        m  = fmaf(p2.x, c2, m);  m8 = fmaf(p2.y, c2, m8);
        m  = fmaf(p3.x, c3, m);  m8 = fmaf(p3.y, c3, m8);
    }
    for (; j < d; j++) {
        unsigned q0 = recs[((size_t)j << 3) + iq];
        float2 p0 = __half22float2(*reinterpret_cast<const __half2*>(&q0));
        int a0 = (int)__shfl(p0.y, 8, 64);
        float c0 = s_rows[a0 * 8 + u];
        m  = fmaf(p0.x, c0, m);
        m8 = fmaf(p0.y, c0, m8);
    }
    s_M[wv][iq * 8 + u] = m;
    if (lane < 8) s_M[wv][64 + u] = m8;

    const float* Bn = s_B + anode * 384;
    float invd = 1.0f / fmaxf((float)d, 1.0f);
    float* row = out + (size_t)node * 144;
    {
        int c = lane;
        int pp, w, ip;
        if (c < 16) { pp = 0; w = c; ip = 0; }
        else { int t = c - 16; pp = 1; w = t / 3; ip = 1 + (t - 3 * (t / 3)); }
        float acc = 0.0f;
        #pragma unroll
        for (int uu = 0; uu < 8; uu++)
            acc = fmaf(Bn[pp * 128 + uu * 16 + w], s_M[wv][ip * 8 + uu], acc);
        row[c] = acc * invd;
    }
    {
        int t = lane;
        int w = t / 5; int i = t - 5 * w;
        float acc = 0.0f;
        #pragma unroll
        for (int uu = 0; uu < 8; uu++)
            acc = fmaf(Bn[256 + uu * 16 + w], s_M[wv][(4 + i) * 8 + uu], acc);
        row[64 + lane] = acc * invd;
    }
    if (lane < 16) {
        int t = 64 + lane;
        int w = t / 5; int i = t - 5 * w;
        float acc = 0.0f;
        #pragma unroll
        for (int uu = 0; uu < 8; uu++)
            acc = fmaf(Bn[256 + uu * 16 + w], s_M[wv][(4 + i) * 8 + uu], acc);
        row[128 + lane] = acc * invd;
    }
}

// ---------------- cooperative mega-kernel ----------------

__global__ __launch_bounds__(256, 4) void mega_kernel(
    const float* pos, const int* A, const int* batch,
    const int* edge_src, const int* edge_dst,
    const float* edge_shifts, const float* cell,
    const float* emb_table,
    const float* w1, const float* b1, const float* w2, const float* b2,
    const float* fc_w1, const float* fc_b1,
    const float* fc_w2, const float* fc_b2,
    const float* fc_w3, const float* fc_b3,
    const float* tp_w,
    float* table, float* rows_g, float* B_g,
    int* deg, int* starts, int* bsum, int* rank, unsigned* records,
    float* out,
    int n_nodes, int n_edges, int n_atom, int n4)
{
    cg::grid_group gg = cg::this_grid();

    __shared__ float s_r[8];
    __shared__ float s_h1[4][64];
    __shared__ int   s_i[256];
    __shared__ int   s_bs[256];
    __shared__ float s_B[3840];
    __shared__ float s_rows[80];
    __shared__ float s_M[4][80];

    int bid = blockIdx.x, tid = threadIdx.x;
    int nblk = gridDim.x;

    // ---- phase A: rows+B (blocks<n_atom), zero deg, table ----
    if (bid < n_atom) {
        int a = bid;
        if (tid < 8) {
            float e[16];
            #pragma unroll
            for (int i = 0; i < 16; i++) e[i] = emb_table[a * 16 + i];
            float acc_j = b2[tid];
            for (int k = 0; k < 64; k++) {
                float acc = b1[k];
                #pragma unroll
                for (int i = 0; i < 16; i++) acc = fmaf(e[i], w1[i * 64 + k], acc);
                acc_j = fmaf(silu(acc), w2[k * 8 + tid], acc_j);
            }
            s_r[tid] = acc_j;
            rows_g[a * 8 + tid] = acc_j;
        }
        __syncthreads();
        for (int t = tid; t < 384; t += 256) {
            int pp = t >> 7, ub = (t >> 4) & 7, wb = t & 15;
            int P = (pp == 0) ? 0 : (pp == 1) ? 3 : 9;
            float acc = 0.0f;
            #pragma unroll
            for (int v = 0; v < 8; v++)
                acc = fmaf(s_r[v], tp_w[P * 1024 + (ub * 8 + v) * 16 + wb], acc);
            B_g[a * 384 + t] = acc;
        }
    }
    for (int i = bid * 256 + tid; i < n4; i += nblk * 256)
        ((int4*)deg)[i] = make_int4(0, 0, 0, 0);
    for (int tb = bid; tb < TBL_N / 4; tb += nblk) {
        __syncthreads();
        table_group(tb * 4 + (tid >> 6), tid >> 6, tid & 63,
                    fc_w1, fc_b1, fc_w2, fc_b2, fc_w3, fc_b3,
                    (float4*)table, s_h1);
    }
    gg.sync();

    // ---- phase B: deg histogram + rank ----
    for (int e = bid * 256 + tid; e < n_edges; e += nblk * 256)
        rank[e] = atomicAdd(&deg[edge_dst[e]], 1);
    gg.sync();

    // ---- phase C: per-256-chunk sums ----
    int nchunks = (n_nodes + 255) >> 8;
    for (int c = bid; c < nchunks; c += nblk) {
        __syncthreads();
        int i = c * 256 + tid;
        s_i[tid] = (i < n_nodes) ? deg[i] : 0;
        __syncthreads();
        #pragma unroll
        for (int off = 128; off > 0; off >>= 1) {
            if (tid < off) s_i[tid] += s_i[tid + off];
            __syncthreads();
        }
        if (tid == 0) bsum[c] = s_i[0];
    }
    gg.sync();

    // ---- phase D: scan chunk sums (replicated) + block scan -> starts ----
    for (int c = bid; c < nchunks; c += nblk) {
        __syncthreads();
        s_bs[tid] = (tid < nchunks) ? bsum[tid] : 0;
        int i = c * 256 + tid;
        int v = (i < n_nodes) ? deg[i] : 0;
        s_i[tid] = v;
        __syncthreads();
        #pragma unroll
        for (int off = 1; off < 256; off <<= 1) {
            int t1 = (tid >= off) ? s_i[tid - off] : 0;
            int t2 = (tid >= off) ? s_bs[tid - off] : 0;
            __syncthreads();
            s_i[tid] += t1;
            s_bs[tid] += t2;
            __syncthreads();
        }
        int base = (c == 0) ? 0 : s_bs[c - 1];
        if (i < n_nodes) starts[i] = base + s_i[tid] - v;
    }
    gg.sync();

    // ---- phase E: edge records ----
    for (int e = bid * 256 + tid; e < n_edges; e += nblk * 256)
        edge_work(e, pos, A, batch, edge_src, edge_dst, edge_shifts, cell,
                  (const float4*)table, starts, rank, records);
    gg.sync();

    // ---- phase F: gather ----
    {
        float4* dB = (float4*)s_B;
        const float4* sB = (const float4*)B_g;
        int nB4 = n_atom * 96;
        for (int t = tid; t < nB4; t += 256) dB[t] = sB[t];
        if (tid < n_atom * 8) s_rows[tid] = rows_g[tid];
    }
    __syncthreads();
    int wv = tid >> 6, lane = tid & 63, iq = lane >> 3, u = lane & 7;
    int n_groups = (n_nodes + 3) >> 2;
    for (int grp = bid; grp < n_groups; grp += nblk) {
        int node = grp * 4 + wv;
        if (node >= n_nodes) continue;
        gather_node(node, wv, lane, iq, u, records, starts, deg, A,
                    s_B, s_rows, s_M, out);
    }
}

// ---------------- fallback 6-kernel path (round-13 proven) ----------------

__global__ __launch_bounds__(256) void setup_kernel(
    const float* __restrict__ emb_table,
    const float* __restrict__ w1, const float* __restrict__ b1,
    const float* __restrict__ w2, const float* __restrict__ b2,
    const float* __restrict__ tp_w,
    const float* __restrict__ fc_w1, const float* __restrict__ fc_b1,
    const float* __restrict__ fc_w2, const float* __restrict__ fc_b2,
    const float* __restrict__ fc_w3, const float* __restrict__ fc_b3,
    float* __restrict__ rows_g, float* __restrict__ B_g,
    float4* __restrict__ table,
    int4* __restrict__ deg4, int n4, int zb, int n_atom)
{
    __shared__ float s_r[8];
    __shared__ float s_h1[4][64];
    int bid = blockIdx.x;
    int tid = threadIdx.x;

    if (bid < zb) {
        int i = bid * 256 + tid;
        if (i < n4) deg4[i] = make_int4(0, 0, 0, 0);
        return;
    }
    if (bid < zb + n_atom) {
        int a = bid - zb;
        if (tid < 8) {
            float e[16];
            #pragma unroll
            for (int i = 0; i < 16; i++) e[i] = emb_table[a * 16 + i];
            float acc_j = b2[tid];
            for (int k = 0; k < 64; k++) {
                float acc = b1[k];
                #pragma unroll
                for (int i = 0; i < 16; i++) acc = fmaf(e[i], w1[i * 64 + k], acc);
                acc_j = fmaf(silu(acc), w2[k * 8 + tid], acc_j);
            }
            s_r[tid] = acc_j;
            rows_g[a * 8 + tid] = acc_j;
        }
        __syncthreads();
        for (int t = tid; t < 384; t += 256) {
            int pp = t >> 7, ub = (t >> 4) & 7, wb = t & 15;
            int P = (pp == 0) ? 0 : (pp == 1) ? 3 : 9;
            float acc = 0.0f;
            #pragma unroll
            for (int v = 0; v < 8; v++)
                acc = fmaf(s_r[v], tp_w[P * 1024 + (ub * 8 + v) * 16 + wb], acc);
            B_g[a * 384 + t] = acc;
        }
        return;
    }
    int tb = bid - zb - n_atom;
    table_group(tb * 4 + (tid >> 6), tid >> 6, tid & 63,
                fc_w1, fc_b1, fc_w2, fc_b2, fc_w3, fc_b3, table, s_h1);
}

__global__ __launch_bounds__(256) void deg_kernel(
    const int* __restrict__ edge_dst, int* __restrict__ deg,
    int* __restrict__ rank, int n_edges)
{
    int e = blockIdx.x * blockDim.x + threadIdx.x;
    if (e >= n_edges) return;
    rank[e] = atomicAdd(&deg[edge_dst[e]], 1);
}

__global__ __launch_bounds__(1024) void partial_kernel(
    const int* __restrict__ deg, int* __restrict__ bsum, int n)
{
    __shared__ int red[1024];
    int tid = threadIdx.x;
    int i = blockIdx.x * 1024 + tid;
    red[tid] = (i < n) ? deg[i] : 0;
    __syncthreads();
    #pragma unroll
    for (int off = 512; off > 0; off >>= 1) {
        if (tid < off) red[tid] += red[tid + off];
        __syncthreads();
    }
    if (tid == 0) bsum[blockIdx.x] = red[0];
}

__global__ __launch_bounds__(1024) void scan_write_kernel(
    const int* __restrict__ deg, const int* __restrict__ bsum,
    int* __restrict__ starts, int n, int nb)
{
    __shared__ int s[1024];
    __shared__ int sb[1024];
    int tid = threadIdx.x;
    sb[tid] = (tid < nb) ? bsum[tid] : 0;
    int i = blockIdx.x * 1024 + tid;
    int v = (i < n) ? deg[i] : 0;
    s[tid] = v;
    __syncthreads();
    #pragma unroll
    for (int off = 1; off < 1024; off <<= 1) {
        int t1 = (tid >= off) ? s[tid - off] : 0;
        int t2 = (tid >= off) ? sb[tid - off] : 0;
        __syncthreads();
        s[tid] += t1;
        sb[tid] += t2;
        __syncthreads();
    }
    int base = (blockIdx.x == 0) ? 0 : sb[blockIdx.x - 1];
    if (i < n) starts[i] = base + s[tid] - v;
}

__global__ __launch_bounds__(256) void edge_kernel(
    const float* __restrict__ pos,
    const int* __restrict__ A,
    const int* __restrict__ batch,
    const int* __restrict__ edge_src,
    const int* __restrict__ edge_dst,
    const float* __restrict__ edge_shifts,
    const float* __restrict__ cell,
    const float4* __restrict__ table,
    const int* __restrict__ starts,
    const int* __restrict__ rank,
    unsigned* __restrict__ records,
    int n_edges)
{
    int e = blockIdx.x * blockDim.x + threadIdx.x;
    if (e >= n_edges) return;
    edge_work(e, pos, A, batch, edge_src, edge_dst, edge_shifts, cell,
              table, starts, rank, records);
}

__global__ __launch_bounds__(256) void gather_kernel(
    const unsigned* __restrict__ records,
    const int* __restrict__ starts,
    const int* __restrict__ deg,
    const int* __restrict__ A,
    const float* __restrict__ rows_g,
    const float* __restrict__ B_g,
    float* __restrict__ out, int n_nodes, int n_atom, int n_groups)
{
    __shared__ float s_B[3840];
    __shared__ float s_rows[80];
    __shared__ float s_M[4][80];
    int tid = threadIdx.x;
    {
        float4* dB = (float4*)s_B;
        const float4* sB = (const float4*)B_g;
        int nB4 = n_atom * 96;
        for (int t = tid; t < nB4; t += 256) dB[t] = sB[t];
        if (tid < n_atom * 8) s_rows[tid] = rows_g[tid];
    }
    __syncthreads();
    int wv = tid >> 6, lane = tid & 63, iq = lane >> 3, u = lane & 7;
    for (int grp = blockIdx.x; grp < n_groups; grp += gridDim.x) {
        int node = grp * 4 + wv;
        if (node >= n_nodes) continue;
        gather_node(node, wv, lane, iq, u, records, starts, deg, A,
                    s_B, s_rows, s_M, out);
    }
}

extern "C" void kernel_launch(void* const* d_in, const int* in_sizes, int n_in,
                              void* d_out, int out_size, void* d_ws, size_t ws_size,
                              hipStream_t stream)
{
    const float* pos         = (const float*)d_in[0];
    const int*   A           = (const int*)d_in[1];
    const int*   batch       = (const int*)d_in[2];
    const int*   edge_src    = (const int*)d_in[3];
    const int*   edge_dst    = (const int*)d_in[4];
    const float* edge_shifts = (const float*)d_in[5];
    const float* cell        = (const float*)d_in[6];
    const float* emb_table   = (const float*)d_in[7];
    const float* mlp_w1      = (const float*)d_in[8];
    const float* mlp_b1      = (const float*)d_in[9];
    const float* mlp_w2      = (const float*)d_in[10];
    const float* mlp_b2      = (const float*)d_in[11];
    const float* fc_w1       = (const float*)d_in[12];
    const float* fc_b1       = (const float*)d_in[13];
    const float* fc_w2       = (const float*)d_in[14];
    const float* fc_b2       = (const float*)d_in[15];
    const float* fc_w3       = (const float*)d_in[16];
    const float* fc_b3       = (const float*)d_in[17];
    const float* tp_w        = (const float*)d_in[18];

    int n_nodes = in_sizes[1];
    int n_edges = in_sizes[3];
    int n_atom  = in_sizes[7] / 16;
    int n4      = (n_nodes + 3) / 4;

    // ws layout (deg padded to n4*4 ints)
    float*    table   = (float*)d_ws;                     // TBL_N*4 floats
    float*    rows_g  = table + (size_t)TBL_N * 4;        // 128 (80 used)
    float*    B_g     = rows_g + 128;                     // 3840
    int*      deg     = (int*)(B_g + 3840);               // n4*4
    int*      starts  = deg + (size_t)n4 * 4;             // n_nodes
    int*      bsum    = starts + n_nodes;                 // 1024
    int*      rank    = bsum + 1024;                      // n_edges
    unsigned* records = (unsigned*)(rank + n_edges);      // n_edges*8 u32

    float* out = (float*)d_out;

    // try cooperative mega-kernel
    int occ = 0;
    hipError_t oerr = hipOccupancyMaxActiveBlocksPerMultiprocessor(
        &occ, mega_kernel, 256, 0);
    if (oerr != hipSuccess || occ < 1) occ = 1;
    int grid = occ * 256;
    if (grid > 2048) grid = 2048;

    void* args[] = {
        (void*)&pos, (void*)&A, (void*)&batch,
        (void*)&edge_src, (void*)&edge_dst,
        (void*)&edge_shifts, (void*)&cell,
        (void*)&emb_table,
        (void*)&mlp_w1, (void*)&mlp_b1, (void*)&mlp_w2, (void*)&mlp_b2,
        (void*)&fc_w1, (void*)&fc_b1, (void*)&fc_w2, (void*)&fc_b2,
        (void*)&fc_w3, (void*)&fc_b3, (void*)&tp_w,
        (void*)&table, (void*)&rows_g, (void*)&B_g,
        (void*)&deg, (void*)&starts, (void*)&bsum, (void*)&rank,
        (void*)&records, (void*)&out,
        (void*)&n_nodes, (void*)&n_edges, (void*)&n_atom, (void*)&n4
    };

    hipError_t lerr = hipLaunchCooperativeKernel(
        (void*)mega_kernel, dim3(grid), dim3(256), args, 0, stream);

    if (lerr != hipSuccess) {
        // fallback: proven 6-kernel path
        int nb = (n_nodes + 1023) / 1024;
        int zb = (n4 + 255) / 256;
        setup_kernel<<<zb + n_atom + TBL_N / 4, 256, 0, stream>>>(
            emb_table, mlp_w1, mlp_b1, mlp_w2, mlp_b2, tp_w,
            fc_w1, fc_b1, fc_w2, fc_b2, fc_w3, fc_b3,
            rows_g, B_g, (float4*)table, (int4*)deg, n4, zb, n_atom);
        deg_kernel<<<(n_edges + 255) / 256, 256, 0, stream>>>(
            edge_dst, deg, rank, n_edges);
        partial_kernel<<<nb, 1024, 0, stream>>>(deg, bsum, n_nodes);
        scan_write_kernel<<<nb, 1024, 0, stream>>>(deg, bsum, starts,
                                                   n_nodes, nb);
        edge_kernel<<<(n_edges + 255) / 256, 256, 0, stream>>>(
            pos, A, batch, edge_src, edge_dst, edge_shifts, cell,
            (const float4*)table, starts, rank, records, n_edges);
        int n_groups = (n_nodes + 3) / 4;
        int ggrid = n_groups < 2048 ? n_groups : 2048;
        gather_kernel<<<ggrid, 256, 0, stream>>>(
            records, starts, deg, A, rows_g, B_g,
            out, n_nodes, n_atom, n_groups);
    }
}

// Round 15
// 97.374 us; speedup vs baseline: 4.7242x; 4.7242x over previous
//
#include <hip/hip_runtime.h>
#include <hip/hip_fp16.h>
#include <cstddef>

// ICTDIrrepsE3Conv — round 15.
//  = round 13 (89.35us, 32B records) with partial+scan_write merged into one
//  scan kernel (6 -> 5 launches). Round 14 post-mortem: cooperative
//  grid.sync() costs ~100us+ per sync on 8-XCD gfx950 — mega-kernel reverted.
//  Merged scan: block b sums chunks [0,b) directly (~3MB total coalesced
//  independent loads, trivial); single variable vs measured baseline.

#define TBL_N 8192
#define TBL_SCALE 1024.0f

__device__ __forceinline__ float silu(float x) {
    return x / (1.0f + __expf(-x));
}

__device__ __forceinline__ unsigned pack_half2(float lo, float hi) {
    unsigned a = __half_as_ushort(__float2half_rn(lo));
    unsigned b = __half_as_ushort(__float2half_rn(hi));
    return (b << 16) | a;
}

// ---- fused setup: blocks [0,zb) zero deg; [zb,zb+n_atom) rows+B;
//      [zb+n_atom, ...) table ----
__global__ __launch_bounds__(256) void setup_kernel(
    const float* __restrict__ emb_table,
    const float* __restrict__ w1, const float* __restrict__ b1,
    const float* __restrict__ w2, const float* __restrict__ b2,
    const float* __restrict__ tp_w,
    const float* __restrict__ fc_w1, const float* __restrict__ fc_b1,
    const float* __restrict__ fc_w2, const float* __restrict__ fc_b2,
    const float* __restrict__ fc_w3, const float* __restrict__ fc_b3,
    float* __restrict__ rows_g, float* __restrict__ B_g,
    float4* __restrict__ table,
    int4* __restrict__ deg4, int n4, int zb, int n_atom)
{
    int bid = blockIdx.x;
    int tid = threadIdx.x;

    if (bid < zb) {
        int i = bid * 256 + tid;
        if (i < n4) deg4[i] = make_int4(0, 0, 0, 0);
        return;
    }
    if (bid < zb + n_atom) {
        __shared__ float s_r[8];
        int a = bid - zb;
        if (tid < 8) {
            float e[16];
            #pragma unroll
            for (int i = 0; i < 16; i++) e[i] = emb_table[a * 16 + i];
            float acc_j = b2[tid];
            for (int k = 0; k < 64; k++) {
                float acc = b1[k];
                #pragma unroll
                for (int i = 0; i < 16; i++) acc = fmaf(e[i], w1[i * 64 + k], acc);
                acc_j = fmaf(silu(acc), w2[k * 8 + tid], acc_j);
            }
            s_r[tid] = acc_j;
            rows_g[a * 8 + tid] = acc_j;
        }
        __syncthreads();
        for (int t = tid; t < 384; t += 256) {
            int pp = t >> 7, ub = (t >> 4) & 7, wb = t & 15;
            int P = (pp == 0) ? 0 : (pp == 1) ? 3 : 9;
            float acc = 0.0f;
            #pragma unroll
            for (int v = 0; v < 8; v++)
                acc = fmaf(s_r[v], tp_w[P * 1024 + (ub * 8 + v) * 16 + wb], acc);
            B_g[a * 384 + t] = acc;
        }
        return;
    }

    // table: 4 samples per block, 1 wave per sample
    __shared__ float s_h1[4][64];
    int tb = bid - zb - n_atom;
    int s = tid >> 6;
    int k = tid & 63;
    int samp = tb * 4 + s;
    float len = (float)samp * (1.0f / TBL_SCALE);

    float emb[16];
    const float inv_step = 17.0f / 5.0f;
    #pragma unroll
    for (int b = 0; b < 16; b++) {
        float d = len * inv_step - (float)(b + 1);
        emb[b] = __expf(-d * d) * 3.5714285714285716f; // 4/1.12
    }

    float acc = fc_b1[k];
    #pragma unroll
    for (int b = 0; b < 16; b++) acc = fmaf(emb[b], fc_w1[b * 64 + k], acc);
    s_h1[s][k] = silu(acc);
    __syncthreads();

    float acc2 = fc_b2[k];
    #pragma unroll
    for (int j = 0; j < 64; j++)
        acc2 = fmaf(s_h1[s][j], fc_w2[j * 64 + k], acc2);
    float h2 = silu(acc2);

    float p0 = h2 * fc_w3[k * 15 + 0];
    float p3 = h2 * fc_w3[k * 15 + 3];
    float p9 = h2 * fc_w3[k * 15 + 9];
    #pragma unroll
    for (int off = 32; off > 0; off >>= 1) {
        p0 += __shfl_down(p0, off, 64);
        p3 += __shfl_down(p3, off, 64);
        p9 += __shfl_down(p9, off, 64);
    }
    if (k == 0) {
        table[samp] = make_float4((fc_b3[0] + p0) * 0.125f,
                                  (fc_b3[3] + p3) * 0.125f,
                                  (fc_b3[9] + p9) * 0.125f, 0.0f);
    }
}

// ---- degree histogram + per-edge rank within its dst bucket ----
__global__ __launch_bounds__(256) void deg_kernel(
    const int* __restrict__ edge_dst, int* __restrict__ deg,
    int* __restrict__ rank, int n_edges)
{
    int e = blockIdx.x * blockDim.x + threadIdx.x;
    if (e >= n_edges) return;
    rank[e] = atomicAdd(&deg[edge_dst[e]], 1);
}

// ---- merged scan: block b sums chunks [0,b) directly, scans its own ----
__global__ __launch_bounds__(1024) void scan_kernel(
    const int* __restrict__ deg, int* __restrict__ starts, int n)
{
    __shared__ int s[1024];
    __shared__ int red[1024];
    int tid = threadIdx.x;
    int b = blockIdx.x;

    // base = sum of all prior chunks (independent coalesced loads)
    int acc = 0;
    for (int c = 0; c < b; c++) {
        int idx = c * 1024 + tid;
        acc += (idx < n) ? deg[idx] : 0;
    }
    red[tid] = acc;
    __syncthreads();
    #pragma unroll
    for (int off = 512; off > 0; off >>= 1) {
        if (tid < off) red[tid] += red[tid + off];
        __syncthreads();
    }
    int base = red[0];

    // inclusive scan of own chunk
    int i = b * 1024 + tid;
    int v = (i < n) ? deg[i] : 0;
    s[tid] = v;
    __syncthreads();
    #pragma unroll
    for (int off = 1; off < 1024; off <<= 1) {
        int t1 = (tid >= off) ? s[tid - off] : 0;
        __syncthreads();
        s[tid] += t1;
        __syncthreads();
    }
    if (i < n) starts[i] = base + s[tid] - v;
}

// ---- per-edge: geometry + table-lerp gates + 32B fp16 record ----
// record (8 dwords): dword k = half2(G_k, aux_k); aux_0=G8, aux_1=asrc, rest 0
__global__ __launch_bounds__(256) void edge_kernel(
    const float* __restrict__ pos,
    const int* __restrict__ A,
    const int* __restrict__ batch,
    const int* __restrict__ edge_src,
    const int* __restrict__ edge_dst,
    const float* __restrict__ edge_shifts,
    const float* __restrict__ cell,
    const float4* __restrict__ table,
    const int* __restrict__ starts,
    const int* __restrict__ rank,
    unsigned* __restrict__ records,
    int n_edges)
{
    int e = blockIdx.x * blockDim.x + threadIdx.x;
    if (e >= n_edges) return;

    int src = edge_src[e];
    int dst = edge_dst[e];

    float sh0 = edge_shifts[3 * (size_t)e + 0];
    float sh1 = edge_shifts[3 * (size_t)e + 1];
    float sh2 = edge_shifts[3 * (size_t)e + 2];
    int g = batch[src];
    const float* C = cell + (size_t)g * 9;
    float shx = sh0 * C[0] + sh1 * C[3] + sh2 * C[6];
    float shy = sh0 * C[1] + sh1 * C[4] + sh2 * C[7];
    float shz = sh0 * C[2] + sh1 * C[5] + sh2 * C[8];

    float vx = pos[3 * (size_t)dst + 0] - pos[3 * (size_t)src + 0] + shx;
    float vy = pos[3 * (size_t)dst + 1] - pos[3 * (size_t)src + 1] + shy;
    float vz = pos[3 * (size_t)dst + 2] - pos[3 * (size_t)src + 2] + shz;

    float len = sqrtf(vx * vx + vy * vy + vz * vz);
    float invl = 1.0f / fmaxf(len, 1e-8f);
    float nx = vx * invl, ny = vy * invl, nz = vz * invl;

    float t = fminf(len * TBL_SCALE, (float)(TBL_N - 1));
    int i0 = (int)t;
    i0 = min(i0, TBL_N - 2);
    float fr = t - (float)i0;
    float4 T0 = table[i0];
    float4 T1 = table[i0 + 1];
    float g0 = fmaf(fr, T1.x - T0.x, T0.x);
    float g1 = fmaf(fr, T1.y - T0.y, T0.y);
    float g2 = fmaf(fr, T1.z - T0.z, T0.z);

    const float s3  = 1.7320508075688772f;
    const float s15 = 3.872983346207417f;
    const float s5  = 2.23606797749979f;
    float G0 = g0;
    float G1 = g1 * s3 * ny, G2 = g1 * s3 * nz, G3 = g1 * s3 * nx;
    float G4 = g2 * s15 * nx * ny;
    float G5 = g2 * s15 * ny * nz;
    float G6 = g2 * 0.5f * s5 * (3.0f * nz * nz - 1.0f);
    float G7 = g2 * s15 * nx * nz;
    float G8 = g2 * 0.5f * s15 * (nx * nx - ny * ny);

    int asrc = A[src];
    int slot = starts[dst] + rank[e];

    uint4* r = (uint4*)(records + (size_t)slot * 8);
    r[0] = make_uint4(pack_half2(G0, G8), pack_half2(G1, (float)asrc),
                      pack_half2(G2, 0.0f), pack_half2(G3, 0.0f));
    r[1] = make_uint4(pack_half2(G4, 0.0f), pack_half2(G5, 0.0f),
                      pack_half2(G6, 0.0f), pack_half2(G7, 0.0f));
}

// ---- gather: grid-stride node-groups; wave per node; per-atom B finish ----
__global__ __launch_bounds__(256) void gather_kernel(
    const unsigned* __restrict__ records,
    const int* __restrict__ starts,
    const int* __restrict__ deg,
    const int* __restrict__ A,
    const float* __restrict__ rows_g,
    const float* __restrict__ B_g,
    float* __restrict__ out, int n_nodes, int n_atom, int n_groups)
{
    __shared__ float s_B[3840];
    __shared__ float s_rows[80];
    __shared__ float s_M[4][80];

    int tid = threadIdx.x;
    {
        float4* dB = (float4*)s_B;
        const float4* sB = (const float4*)B_g;
        int nB4 = n_atom * 96;
        for (int t = tid; t < nB4; t += 256) dB[t] = sB[t];
        if (tid < n_atom * 8) s_rows[tid] = rows_g[tid];
    }
    __syncthreads();

    int wv = tid >> 6;
    int lane = tid & 63;
    int iq = lane >> 3, u = lane & 7;

    for (int grp = blockIdx.x; grp < n_groups; grp += gridDim.x) {
        int node = grp * 4 + wv;
        if (node >= n_nodes) continue;

        int start = starts[node];
        int d = deg[node];
        int anode = A[node];

        float m = 0.0f, m8 = 0.0f;
        const unsigned* recs = records + (size_t)start * 8;
        int j = 0;
        for (; j + 4 <= d; j += 4) {
            unsigned q0 = recs[((size_t)(j + 0) << 3) + iq];
            unsigned q1 = recs[((size_t)(j + 1) << 3) + iq];
            unsigned q2 = recs[((size_t)(j + 2) << 3) + iq];
            unsigned q3 = recs[((size_t)(j + 3) << 3) + iq];
            float2 p0 = __half22float2(*reinterpret_cast<const __half2*>(&q0));
            float2 p1 = __half22float2(*reinterpret_cast<const __half2*>(&q1));
            float2 p2 = __half22float2(*reinterpret_cast<const __half2*>(&q2));
            float2 p3 = __half22float2(*reinterpret_cast<const __half2*>(&q3));
            int a0 = (int)__shfl(p0.y, 8, 64);
            int a1 = (int)__shfl(p1.y, 8, 64);
            int a2 = (int)__shfl(p2.y, 8, 64);
            int a3 = (int)__shfl(p3.y, 8, 64);
            float c0 = s_rows[a0 * 8 + u];
            float c1 = s_rows[a1 * 8 + u];
            float c2 = s_rows[a2 * 8 + u];
            float c3 = s_rows[a3 * 8 + u];
            m  = fmaf(p0.x, c0, m);  m8 = fmaf(p0.y, c0, m8);
            m  = fmaf(p1.x, c1, m);  m8 = fmaf(p1.y, c1, m8);
            m  = fmaf(p2.x, c2, m);  m8 = fmaf(p2.y, c2, m8);
            m  = fmaf(p3.x, c3, m);  m8 = fmaf(p3.y, c3, m8);
        }
        for (; j < d; j++) {
            unsigned q0 = recs[((size_t)j << 3) + iq];
            float2 p0 = __half22float2(*reinterpret_cast<const __half2*>(&q0));
            int a0 = (int)__shfl(p0.y, 8, 64);
            float c0 = s_rows[a0 * 8 + u];
            m  = fmaf(p0.x, c0, m);
            m8 = fmaf(p0.y, c0, m8);
        }
        s_M[wv][iq * 8 + u] = m;
        if (lane < 8) s_M[wv][64 + u] = m8;

        const float* Bn = s_B + anode * 384;
        float invd = 1.0f / fmaxf((float)d, 1.0f);
        float* row = out + (size_t)node * 144;
        {
            int c = lane;
            int pp, w, ip;
            if (c < 16) { pp = 0; w = c; ip = 0; }
            else { int t = c - 16; pp = 1; w = t / 3; ip = 1 + (t - 3 * (t / 3)); }
            float acc = 0.0f;
            #pragma unroll
            for (int uu = 0; uu < 8; uu++)
                acc = fmaf(Bn[pp * 128 + uu * 16 + w], s_M[wv][ip * 8 + uu], acc);
            row[c] = acc * invd;
        }
        {
            int t = lane;
            int w = t / 5; int i = t - 5 * w;
            float acc = 0.0f;
            #pragma unroll
            for (int uu = 0; uu < 8; uu++)
                acc = fmaf(Bn[256 + uu * 16 + w], s_M[wv][(4 + i) * 8 + uu], acc);
            row[64 + lane] = acc * invd;
        }
        if (lane < 16) {
            int t = 64 + lane;
            int w = t / 5; int i = t - 5 * w;
            float acc = 0.0f;
            #pragma unroll
            for (int uu = 0; uu < 8; uu++)
                acc = fmaf(Bn[256 + uu * 16 + w], s_M[wv][(4 + i) * 8 + uu], acc);
            row[128 + lane] = acc * invd;
        }
    }
}

extern "C" void kernel_launch(void* const* d_in, const int* in_sizes, int n_in,
                              void* d_out, int out_size, void* d_ws, size_t ws_size,
                              hipStream_t stream)
{
    const float* pos         = (const float*)d_in[0];
    const int*   A           = (const int*)d_in[1];
    const int*   batch       = (const int*)d_in[2];
    const int*   edge_src    = (const int*)d_in[3];
    const int*   edge_dst    = (const int*)d_in[4];
    const float* edge_shifts = (const float*)d_in[5];
    const float* cell        = (const float*)d_in[6];
    const float* emb_table   = (const float*)d_in[7];
    const float* mlp_w1      = (const float*)d_in[8];
    const float* mlp_b1      = (const float*)d_in[9];
    const float* mlp_w2      = (const float*)d_in[10];
    const float* mlp_b2      = (const float*)d_in[11];
    const float* fc_w1       = (const float*)d_in[12];
    const float* fc_b1       = (const float*)d_in[13];
    const float* fc_w2       = (const float*)d_in[14];
    const float* fc_b2       = (const float*)d_in[15];
    const float* fc_w3       = (const float*)d_in[16];
    const float* fc_b3       = (const float*)d_in[17];
    const float* tp_w        = (const float*)d_in[18];

    int n_nodes = in_sizes[1];
    int n_edges = in_sizes[3];
    int n_atom  = in_sizes[7] / 16;
    int nb      = (n_nodes + 1023) / 1024;

    // ws layout
    float*    table   = (float*)d_ws;                     // TBL_N*4 floats
    float*    rows_g  = table + (size_t)TBL_N * 4;        // 128 (80 used)
    float*    B_g     = rows_g + 128;                     // 3840
    int*      deg     = (int*)(B_g + 3840);               // n_nodes
    int*      starts  = deg + n_nodes;                    // n_nodes
    int*      rank    = starts + n_nodes;                 // n_edges
    unsigned* records = (unsigned*)(rank + n_edges);      // n_edges*8 u32

    int n4 = (n_nodes + 3) / 4;
    int zb = (n4 + 255) / 256;

    setup_kernel<<<zb + n_atom + TBL_N / 4, 256, 0, stream>>>(
        emb_table, mlp_w1, mlp_b1, mlp_w2, mlp_b2, tp_w,
        fc_w1, fc_b1, fc_w2, fc_b2, fc_w3, fc_b3,
        rows_g, B_g, (float4*)table, (int4*)deg, n4, zb, n_atom);

    deg_kernel<<<(n_edges + 255) / 256, 256, 0, stream>>>(
        edge_dst, deg, rank, n_edges);

    scan_kernel<<<nb, 1024, 0, stream>>>(deg, starts, n_nodes);

    edge_kernel<<<(n_edges + 255) / 256, 256, 0, stream>>>(
        pos, A, batch, edge_src, edge_dst, edge_shifts, cell,
        (const float4*)table, starts, rank, records, n_edges);

    int n_groups = (n_nodes + 3) / 4;
    int ggrid = n_groups < 2048 ? n_groups : 2048;
    gather_kernel<<<ggrid, 256, 0, stream>>>(
        records, starts, deg, A, rows_g, B_g,
        (float*)d_out, n_nodes, n_atom, n_groups);
}

// Round 16
// 88.738 us; speedup vs baseline: 5.1840x; 1.0973x over previous
//
#include <hip/hip_runtime.h>
#include <hip/hip_fp16.h>
#include <cstddef>

// ICTDIrrepsE3Conv — round 16: revert to round-13 configuration (best
// measured family: 89.29/89.35us). Round 15 A/B proved merged O(b) scan
// is a +8us regressor -> restore two-kernel parallel scan.
//  - gates = f(edge_length) only -> 8192-entry lerp table
//  - atom-type factorization: rows[10][8], B[10][3][8][16] precomputed
//  - 32B fp16 records (aux lane-8 carries asrc), rank trick (no edge atomics)
//  - grid-stride gather (2048 blocks), per-atom B finish
// Ledger: scatter->gather 9x; table 2.8x; fill/scan/table launch-shape fixes;
// record fp16 -7us; grid-stride -7us. Regressors (reverted): byte-sidecar,
// merged scan, cooperative mega-kernel (grid.sync ~100us+ on 8 XCDs).

#define TBL_N 8192
#define TBL_SCALE 1024.0f

__device__ __forceinline__ float silu(float x) {
    return x / (1.0f + __expf(-x));
}

__device__ __forceinline__ unsigned pack_half2(float lo, float hi) {
    unsigned a = __half_as_ushort(__float2half_rn(lo));
    unsigned b = __half_as_ushort(__float2half_rn(hi));
    return (b << 16) | a;
}

// ---- fused setup: blocks [0,zb) zero deg; [zb,zb+n_atom) rows+B;
//      [zb+n_atom, ...) table ----
__global__ __launch_bounds__(256) void setup_kernel(
    const float* __restrict__ emb_table,
    const float* __restrict__ w1, const float* __restrict__ b1,
    const float* __restrict__ w2, const float* __restrict__ b2,
    const float* __restrict__ tp_w,
    const float* __restrict__ fc_w1, const float* __restrict__ fc_b1,
    const float* __restrict__ fc_w2, const float* __restrict__ fc_b2,
    const float* __restrict__ fc_w3, const float* __restrict__ fc_b3,
    float* __restrict__ rows_g, float* __restrict__ B_g,
    float4* __restrict__ table,
    int4* __restrict__ deg4, int n4, int zb, int n_atom)
{
    int bid = blockIdx.x;
    int tid = threadIdx.x;

    if (bid < zb) {
        int i = bid * 256 + tid;
        if (i < n4) deg4[i] = make_int4(0, 0, 0, 0);
        return;
    }
    if (bid < zb + n_atom) {
        __shared__ float s_r[8];
        int a = bid - zb;
        if (tid < 8) {
            float e[16];
            #pragma unroll
            for (int i = 0; i < 16; i++) e[i] = emb_table[a * 16 + i];
            float acc_j = b2[tid];
            for (int k = 0; k < 64; k++) {
                float acc = b1[k];
                #pragma unroll
                for (int i = 0; i < 16; i++) acc = fmaf(e[i], w1[i * 64 + k], acc);
                acc_j = fmaf(silu(acc), w2[k * 8 + tid], acc_j);
            }
            s_r[tid] = acc_j;
            rows_g[a * 8 + tid] = acc_j;
        }
        __syncthreads();
        for (int t = tid; t < 384; t += 256) {
            int pp = t >> 7, ub = (t >> 4) & 7, wb = t & 15;
            int P = (pp == 0) ? 0 : (pp == 1) ? 3 : 9;
            float acc = 0.0f;
            #pragma unroll
            for (int v = 0; v < 8; v++)
                acc = fmaf(s_r[v], tp_w[P * 1024 + (ub * 8 + v) * 16 + wb], acc);
            B_g[a * 384 + t] = acc;
        }
        return;
    }

    // table: 4 samples per block, 1 wave per sample
    __shared__ float s_h1[4][64];
    int tb = bid - zb - n_atom;
    int s = tid >> 6;
    int k = tid & 63;
    int samp = tb * 4 + s;
    float len = (float)samp * (1.0f / TBL_SCALE);

    float emb[16];
    const float inv_step = 17.0f / 5.0f;
    #pragma unroll
    for (int b = 0; b < 16; b++) {
        float d = len * inv_step - (float)(b + 1);
        emb[b] = __expf(-d * d) * 3.5714285714285716f; // 4/1.12
    }

    float acc = fc_b1[k];
    #pragma unroll
    for (int b = 0; b < 16; b++) acc = fmaf(emb[b], fc_w1[b * 64 + k], acc);
    s_h1[s][k] = silu(acc);
    __syncthreads();

    float acc2 = fc_b2[k];
    #pragma unroll
    for (int j = 0; j < 64; j++)
        acc2 = fmaf(s_h1[s][j], fc_w2[j * 64 + k], acc2);
    float h2 = silu(acc2);

    float p0 = h2 * fc_w3[k * 15 + 0];
    float p3 = h2 * fc_w3[k * 15 + 3];
    float p9 = h2 * fc_w3[k * 15 + 9];
    #pragma unroll
    for (int off = 32; off > 0; off >>= 1) {
        p0 += __shfl_down(p0, off, 64);
        p3 += __shfl_down(p3, off, 64);
        p9 += __shfl_down(p9, off, 64);
    }
    if (k == 0) {
        table[samp] = make_float4((fc_b3[0] + p0) * 0.125f,
                                  (fc_b3[3] + p3) * 0.125f,
                                  (fc_b3[9] + p9) * 0.125f, 0.0f);
    }
}

// ---- degree histogram + per-edge rank within its dst bucket ----
__global__ __launch_bounds__(256) void deg_kernel(
    const int* __restrict__ edge_dst, int* __restrict__ deg,
    int* __restrict__ rank, int n_edges)
{
    int e = blockIdx.x * blockDim.x + threadIdx.x;
    if (e >= n_edges) return;
    rank[e] = atomicAdd(&deg[edge_dst[e]], 1);
}

__global__ __launch_bounds__(1024) void partial_kernel(
    const int* __restrict__ deg, int* __restrict__ bsum, int n)
{
    __shared__ int red[1024];
    int tid = threadIdx.x;
    int i = blockIdx.x * 1024 + tid;
    red[tid] = (i < n) ? deg[i] : 0;
    __syncthreads();
    #pragma unroll
    for (int off = 512; off > 0; off >>= 1) {
        if (tid < off) red[tid] += red[tid + off];
        __syncthreads();
    }
    if (tid == 0) bsum[blockIdx.x] = red[0];
}

__global__ __launch_bounds__(1024) void scan_write_kernel(
    const int* __restrict__ deg, const int* __restrict__ bsum,
    int* __restrict__ starts, int n, int nb)
{
    __shared__ int s[1024];
    __shared__ int sb[1024];
    int tid = threadIdx.x;

    sb[tid] = (tid < nb) ? bsum[tid] : 0;
    int i = blockIdx.x * 1024 + tid;
    int v = (i < n) ? deg[i] : 0;
    s[tid] = v;
    __syncthreads();
    #pragma unroll
    for (int off = 1; off < 1024; off <<= 1) {
        int t1 = (tid >= off) ? s[tid - off] : 0;
        int t2 = (tid >= off) ? sb[tid - off] : 0;
        __syncthreads();
        s[tid] += t1;
        sb[tid] += t2;
        __syncthreads();
    }
    int base = (blockIdx.x == 0) ? 0 : sb[blockIdx.x - 1];
    if (i < n) starts[i] = base + s[tid] - v;
}

// ---- per-edge: geometry + table-lerp gates + 32B fp16 record ----
// record (8 dwords): dword k = half2(G_k, aux_k); aux_0=G8, aux_1=asrc, rest 0
__global__ __launch_bounds__(256) void edge_kernel(
    const float* __restrict__ pos,
    const int* __restrict__ A,
    const int* __restrict__ batch,
    const int* __restrict__ edge_src,
    const int* __restrict__ edge_dst,
    const float* __restrict__ edge_shifts,
    const float* __restrict__ cell,
    const float4* __restrict__ table,
    const int* __restrict__ starts,
    const int* __restrict__ rank,
    unsigned* __restrict__ records,
    int n_edges)
{
    int e = blockIdx.x * blockDim.x + threadIdx.x;
    if (e >= n_edges) return;

    int src = edge_src[e];
    int dst = edge_dst[e];

    float sh0 = edge_shifts[3 * (size_t)e + 0];
    float sh1 = edge_shifts[3 * (size_t)e + 1];
    float sh2 = edge_shifts[3 * (size_t)e + 2];
    int g = batch[src];
    const float* C = cell + (size_t)g * 9;
    float shx = sh0 * C[0] + sh1 * C[3] + sh2 * C[6];
    float shy = sh0 * C[1] + sh1 * C[4] + sh2 * C[7];
    float shz = sh0 * C[2] + sh1 * C[5] + sh2 * C[8];

    float vx = pos[3 * (size_t)dst + 0] - pos[3 * (size_t)src + 0] + shx;
    float vy = pos[3 * (size_t)dst + 1] - pos[3 * (size_t)src + 1] + shy;
    float vz = pos[3 * (size_t)dst + 2] - pos[3 * (size_t)src + 2] + shz;

    float len = sqrtf(vx * vx + vy * vy + vz * vz);
    float invl = 1.0f / fmaxf(len, 1e-8f);
    float nx = vx * invl, ny = vy * invl, nz = vz * invl;

    float t = fminf(len * TBL_SCALE, (float)(TBL_N - 1));
    int i0 = (int)t;
    i0 = min(i0, TBL_N - 2);
    float fr = t - (float)i0;
    float4 T0 = table[i0];
    float4 T1 = table[i0 + 1];
    float g0 = fmaf(fr, T1.x - T0.x, T0.x);
    float g1 = fmaf(fr, T1.y - T0.y, T0.y);
    float g2 = fmaf(fr, T1.z - T0.z, T0.z);

    const float s3  = 1.7320508075688772f;
    const float s15 = 3.872983346207417f;
    const float s5  = 2.23606797749979f;
    float G0 = g0;
    float G1 = g1 * s3 * ny, G2 = g1 * s3 * nz, G3 = g1 * s3 * nx;
    float G4 = g2 * s15 * nx * ny;
    float G5 = g2 * s15 * ny * nz;
    float G6 = g2 * 0.5f * s5 * (3.0f * nz * nz - 1.0f);
    float G7 = g2 * s15 * nx * nz;
    float G8 = g2 * 0.5f * s15 * (nx * nx - ny * ny);

    int asrc = A[src];
    int slot = starts[dst] + rank[e];

    uint4* r = (uint4*)(records + (size_t)slot * 8);
    r[0] = make_uint4(pack_half2(G0, G8), pack_half2(G1, (float)asrc),
                      pack_half2(G2, 0.0f), pack_half2(G3, 0.0f));
    r[1] = make_uint4(pack_half2(G4, 0.0f), pack_half2(G5, 0.0f),
                      pack_half2(G6, 0.0f), pack_half2(G7, 0.0f));
}

// ---- gather: grid-stride node-groups; wave per node; per-atom B finish ----
__global__ __launch_bounds__(256) void gather_kernel(
    const unsigned* __restrict__ records,
    const int* __restrict__ starts,
    const int* __restrict__ deg,
    const int* __restrict__ A,
    const float* __restrict__ rows_g,
    const float* __restrict__ B_g,
    float* __restrict__ out, int n_nodes, int n_atom, int n_groups)
{
    __shared__ float s_B[3840];
    __shared__ float s_rows[80];
    __shared__ float s_M[4][80];

    int tid = threadIdx.x;
    {
        float4* dB = (float4*)s_B;
        const float4* sB = (const float4*)B_g;
        int nB4 = n_atom * 96;
        for (int t = tid; t < nB4; t += 256) dB[t] = sB[t];
        if (tid < n_atom * 8) s_rows[tid] = rows_g[tid];
    }
    __syncthreads();

    int wv = tid >> 6;
    int lane = tid & 63;
    int iq = lane >> 3, u = lane & 7;

    for (int grp = blockIdx.x; grp < n_groups; grp += gridDim.x) {
        int node = grp * 4 + wv;
        if (node >= n_nodes) continue;

        int start = starts[node];
        int d = deg[node];
        int anode = A[node];

        float m = 0.0f, m8 = 0.0f;
        const unsigned* recs = records + (size_t)start * 8;
        int j = 0;
        for (; j + 4 <= d; j += 4) {
            unsigned q0 = recs[((size_t)(j + 0) << 3) + iq];
            unsigned q1 = recs[((size_t)(j + 1) << 3) + iq];
            unsigned q2 = recs[((size_t)(j + 2) << 3) + iq];
            unsigned q3 = recs[((size_t)(j + 3) << 3) + iq];
            float2 p0 = __half22float2(*reinterpret_cast<const __half2*>(&q0));
            float2 p1 = __half22float2(*reinterpret_cast<const __half2*>(&q1));
            float2 p2 = __half22float2(*reinterpret_cast<const __half2*>(&q2));
            float2 p3 = __half22float2(*reinterpret_cast<const __half2*>(&q3));
            int a0 = (int)__shfl(p0.y, 8, 64);
            int a1 = (int)__shfl(p1.y, 8, 64);
            int a2 = (int)__shfl(p2.y, 8, 64);
            int a3 = (int)__shfl(p3.y, 8, 64);
            float c0 = s_rows[a0 * 8 + u];
            float c1 = s_rows[a1 * 8 + u];
            float c2 = s_rows[a2 * 8 + u];
            float c3 = s_rows[a3 * 8 + u];
            m  = fmaf(p0.x, c0, m);  m8 = fmaf(p0.y, c0, m8);
            m  = fmaf(p1.x, c1, m);  m8 = fmaf(p1.y, c1, m8);
            m  = fmaf(p2.x, c2, m);  m8 = fmaf(p2.y, c2, m8);
            m  = fmaf(p3.x, c3, m);  m8 = fmaf(p3.y, c3, m8);
        }
        for (; j < d; j++) {
            unsigned q0 = recs[((size_t)j << 3) + iq];
            float2 p0 = __half22float2(*reinterpret_cast<const __half2*>(&q0));
            int a0 = (int)__shfl(p0.y, 8, 64);
            float c0 = s_rows[a0 * 8 + u];
            m  = fmaf(p0.x, c0, m);
            m8 = fmaf(p0.y, c0, m8);
        }
        s_M[wv][iq * 8 + u] = m;
        if (lane < 8) s_M[wv][64 + u] = m8;

        const float* Bn = s_B + anode * 384;
        float invd = 1.0f / fmaxf((float)d, 1.0f);
        float* row = out + (size_t)node * 144;
        {
            int c = lane;
            int pp, w, ip;
            if (c < 16) { pp = 0; w = c; ip = 0; }
            else { int t = c - 16; pp = 1; w = t / 3; ip = 1 + (t - 3 * (t / 3)); }
            float acc = 0.0f;
            #pragma unroll
            for (int uu = 0; uu < 8; uu++)
                acc = fmaf(Bn[pp * 128 + uu * 16 + w], s_M[wv][ip * 8 + uu], acc);
            row[c] = acc * invd;
        }
        {
            int t = lane;
            int w = t / 5; int i = t - 5 * w;
            float acc = 0.0f;
            #pragma unroll
            for (int uu = 0; uu < 8; uu++)
                acc = fmaf(Bn[256 + uu * 16 + w], s_M[wv][(4 + i) * 8 + uu], acc);
            row[64 + lane] = acc * invd;
        }
        if (lane < 16) {
            int t = 64 + lane;
            int w = t / 5; int i = t - 5 * w;
            float acc = 0.0f;
            #pragma unroll
            for (int uu = 0; uu < 8; uu++)
                acc = fmaf(Bn[256 + uu * 16 + w], s_M[wv][(4 + i) * 8 + uu], acc);
            row[128 + lane] = acc * invd;
        }
    }
}

extern "C" void kernel_launch(void* const* d_in, const int* in_sizes, int n_in,
                              void* d_out, int out_size, void* d_ws, size_t ws_size,
                              hipStream_t stream)
{
    const float* pos         = (const float*)d_in[0];
    const int*   A           = (const int*)d_in[1];
    const int*   batch       = (const int*)d_in[2];
    const int*   edge_src    = (const int*)d_in[3];
    const int*   edge_dst    = (const int*)d_in[4];
    const float* edge_shifts = (const float*)d_in[5];
    const float* cell        = (const float*)d_in[6];
    const float* emb_table   = (const float*)d_in[7];
    const float* mlp_w1      = (const float*)d_in[8];
    const float* mlp_b1      = (const float*)d_in[9];
    const float* mlp_w2      = (const float*)d_in[10];
    const float* mlp_b2      = (const float*)d_in[11];
    const float* fc_w1       = (const float*)d_in[12];
    const float* fc_b1       = (const float*)d_in[13];
    const float* fc_w2       = (const float*)d_in[14];
    const float* fc_b2       = (const float*)d_in[15];
    const float* fc_w3       = (const float*)d_in[16];
    const float* fc_b3       = (const float*)d_in[17];
    const float* tp_w        = (const float*)d_in[18];

    int n_nodes = in_sizes[1];
    int n_edges = in_sizes[3];
    int n_atom  = in_sizes[7] / 16;
    int nb      = (n_nodes + 1023) / 1024;

    // ws layout
    float*    table   = (float*)d_ws;                     // TBL_N*4 floats
    float*    rows_g  = table + (size_t)TBL_N * 4;        // 128 (80 used)
    float*    B_g     = rows_g + 128;                     // 3840
    int*      deg     = (int*)(B_g + 3840);               // n_nodes
    int*      starts  = deg + n_nodes;                    // n_nodes
    int*      bsum    = starts + n_nodes;                 // 1024
    int*      rank    = bsum + 1024;                      // n_edges
    unsigned* records = (unsigned*)(rank + n_edges);      // n_edges*8 u32

    int n4 = (n_nodes + 3) / 4;
    int zb = (n4 + 255) / 256;

    setup_kernel<<<zb + n_atom + TBL_N / 4, 256, 0, stream>>>(
        emb_table, mlp_w1, mlp_b1, mlp_w2, mlp_b2, tp_w,
        fc_w1, fc_b1, fc_w2, fc_b2, fc_w3, fc_b3,
        rows_g, B_g, (float4*)table, (int4*)deg, n4, zb, n_atom);

    deg_kernel<<<(n_edges + 255) / 256, 256, 0, stream>>>(
        edge_dst, deg, rank, n_edges);

    partial_kernel<<<nb, 1024, 0, stream>>>(deg, bsum, n_nodes);

    scan_write_kernel<<<nb, 1024, 0, stream>>>(deg, bsum, starts, n_nodes, nb);

    edge_kernel<<<(n_edges + 255) / 256, 256, 0, stream>>>(
        pos, A, batch, edge_src, edge_dst, edge_shifts, cell,
        (const float4*)table, starts, rank, records, n_edges);

    int n_groups = (n_nodes + 3) / 4;
    int ggrid = n_groups < 2048 ? n_groups : 2048;
    gather_kernel<<<ggrid, 256, 0, stream>>>(
        records, starts, deg, A, rows_g, B_g,
        (float*)d_out, n_nodes, n_atom, n_groups);
}